// Round 10
// baseline (2361.069 us; speedup 1.0000x reference)
//
#include <hip/hip_runtime.h>

#define BN_EPS 1e-5f
#define CAP 3072   // per-bucket edge capacity (mean 1805, +30 sigma; guarded)

using bf16x8 = __attribute__((ext_vector_type(8))) short;
using f32x4  = __attribute__((ext_vector_type(4))) float;

__device__ __forceinline__ unsigned int f2bf(float f) {   // RTNE fp32->bf16
    unsigned int u = __float_as_uint(f);
    u += 0x7fffu + ((u >> 16) & 1u);
    return u >> 16;
}
// packed RTNE fp32x2 -> bf16x2 (bit-identical to f2bf pair)
__device__ __forceinline__ unsigned int f2bf2(float lo, float hi) {
    unsigned int r;
    asm("v_cvt_pk_bf16_f32 %0, %1, %2" : "=v"(r) : "v"(lo), "v"(hi));
    return r;
}
__device__ __forceinline__ float bflo(unsigned int u) { return __uint_as_float(u << 16); }
__device__ __forceinline__ float bfhi(unsigned int u) { return __uint_as_float(u & 0xffff0000u); }

// ========= dispatch 1: weight prep (+ bcur/stats init, own dispatch) ========
// MUST complete before k_bscatter (bcur init -> atomicAdd ordering).
// stats = 2 layers x 8 slabs x 256 floats = 4096 floats zeroed.
__global__ __launch_bounds__(256) void k_prepW3(const float* __restrict__ W0,
                                                const float* __restrict__ W1,
                                                const float* __restrict__ W2,
                                                unsigned short* __restrict__ Wf,
                                                int* __restrict__ bcur,
                                                float* __restrict__ stats, int NB) {
    int t = blockIdx.x * 256 + threadIdx.x;   // 0..6143
    if (t < NB) bcur[t] = t * CAP;            // folded k_init
    if (t < 4096) stats[t] = 0.f;             // zeroes stats0+stats1 slabs
    int wid = t >> 11;                        // 0,1,2
    int f = t & 2047;
    const float* W = (wid == 0) ? W0 : (wid == 1) ? W1 : W2;
    int C = (wid == 2) ? 40 : 128;
    int lane = f & 63, frag = f >> 6;
    int kt = frag & 3, ct = frag >> 2;
    int r = lane & 15, q = lane >> 4;
    int col = ct * 16 + r;
    int kbase = kt * 32 + q * 8;
    unsigned int v[8];
    #pragma unroll
    for (int j = 0; j < 8; ++j)
        v[j] = (col < C) ? f2bf(W[(size_t)(kbase + j) * C + col]) : 0u;
    uint4 o;
    o.x = v[0] | (v[1] << 16);
    o.y = v[2] | (v[3] << 16);
    o.z = v[4] | (v[5] << 16);
    o.w = v[6] | (v[7] << 16);
    ((uint4*)Wf)[t] = o;
}

// ===================== scatter edges into fixed buckets =====================
__global__ __launch_bounds__(256) void k_bscatter(const int* __restrict__ ei,
                                                  int* __restrict__ bcur,
                                                  unsigned int* __restrict__ ebuf,
                                                  int E, int NB) {
    __shared__ int h[768];
    __shared__ int wb[768];
    for (int i = threadIdx.x; i < 768; i += 256) h[i] = 0;
    __syncthreads();
    int base = blockIdx.x * 8192;
    int rk[32];
    #pragma unroll
    for (int it = 0; it < 32; ++it) {
        int e = base + it * 256 + threadIdx.x;
        rk[it] = (e < E) ? atomicAdd(&h[ei[E + e] >> 8], 1) : 0;
    }
    __syncthreads();
    for (int i = threadIdx.x; i < NB; i += 256) {
        int c = h[i];
        wb[i] = c ? atomicAdd(&bcur[i], c) : 0;
    }
    __syncthreads();
    #pragma unroll
    for (int it = 0; it < 32; ++it) {
        int e = base + it * 256 + threadIdx.x;
        if (e < E) {
            unsigned s = (unsigned)ei[e], d = (unsigned)ei[E + e];
            int bk = (int)(d >> 8);
            int pos = wb[bk] + rk[it];
            if (pos >= bk * CAP && pos < (bk + 1) * CAP)   // two-sided guard
                ebuf[pos] = s | ((d & 255u) << 24);
        }
    }
}

// ============ dispatch 3: CSR finalize || layer-0 GEMM (independent) ========
// blocks [0,NB): bfinal role (consumes ebuf/bcur from dispatch 2).
// blocks [NB, NB+gemm_grid): gemm0 role (consumes Wf from dispatch 1 + x).
// No intra-dispatch producer-consumer: race-free.
__global__ __launch_bounds__(256) void k_final_gemm0(
        const unsigned int* __restrict__ ebuf, const int* __restrict__ bcur,
        int* __restrict__ csr, int* __restrict__ rs, int* __restrict__ re,
        float* __restrict__ dinv,
        const float* __restrict__ X, const unsigned short* __restrict__ Wf,
        unsigned short* __restrict__ H, int N, int NB) {
    __shared__ int cnt[256];
    __shared__ int scn[256];
    __shared__ int cur[256];
    __shared__ unsigned short bF[8 * 4 * 512];
    const int t = threadIdx.x;
    if (blockIdx.x < (unsigned)NB) {
        // ---- bfinal role ----
        const int b = blockIdx.x;
        const int beg = b * CAP;
        const int cntE = min(bcur[b] - beg, CAP);
        cnt[t] = 0;
        __syncthreads();
        for (int j = t; j < cntE; j += 256)
            atomicAdd(&cnt[ebuf[beg + j] >> 24], 1);
        __syncthreads();
        int v = cnt[t];
        scn[t] = v;
        __syncthreads();
        for (int off = 1; off < 256; off <<= 1) {
            int x = (t >= off) ? scn[t - off] : 0;
            __syncthreads();
            scn[t] += x;
            __syncthreads();
        }
        int excl = scn[t] - v;
        int node = b * 256 + t;
        if (node < N) {
            rs[node]   = beg + excl;
            re[node]   = beg + excl + v;
            dinv[node] = rsqrtf((float)(1 + v));   // +1 self-loop
        }
        cur[t] = beg + excl;
        __syncthreads();
        for (int j = t; j < cntE; j += 256) {
            unsigned e = ebuf[beg + j];
            int pos = atomicAdd(&cur[e >> 24], 1);
            csr[pos] = (int)(e & 0x00FFFFFFu);
        }
        return;
    }
    // ---- gemm0 role: H[N,128] = bf16(X[N,128]_f32 @ W0) ----
    const int rowbase = (blockIdx.x - NB) * 64;
    {   // stage B: 8 col-tiles
        const uint4* src = (const uint4*)Wf;
        uint4* dst = (uint4*)bF;
        #pragma unroll
        for (int i = 0; i < 8; ++i) dst[t + 256 * i] = src[t + 256 * i];
    }
    __syncthreads();

    const int wave = t >> 6, lane = t & 63;
    const int r = lane & 15, q = lane >> 4;
    const int row  = rowbase + wave * 16 + r;
    const int rowc = min(row, N - 1);          // clamp: OOB rows computed, not stored

    bf16x8 afr[4];
    #pragma unroll
    for (int kt = 0; kt < 4; ++kt) {
        const int kc = kt * 32 + q * 8;
        const float4* xp = (const float4*)(X + (size_t)rowc * 128 + kc);
        float4 p0 = xp[0], p1 = xp[1];
        union { unsigned int u[4]; bf16x8 v; } pk;
        pk.u[0] = f2bf2(p0.x, p0.y);
        pk.u[1] = f2bf2(p0.z, p0.w);
        pk.u[2] = f2bf2(p1.x, p1.y);
        pk.u[3] = f2bf2(p1.z, p1.w);
        afr[kt] = pk.v;
    }

    f32x4 acc[8];
    #pragma unroll
    for (int ct = 0; ct < 8; ++ct) acc[ct] = (f32x4){0.f, 0.f, 0.f, 0.f};
    #pragma unroll
    for (int kt = 0; kt < 4; ++kt) {
        #pragma unroll
        for (int ct = 0; ct < 8; ++ct) {
            bf16x8 b = ((const bf16x8*)bF)[(ct * 4 + kt) * 64 + lane];
            acc[ct] = __builtin_amdgcn_mfma_f32_16x16x32_bf16(afr[kt], b, acc[ct], 0, 0, 0);
        }
    }
    #pragma unroll
    for (int ct = 0; ct < 8; ++ct) {
        #pragma unroll
        for (int i = 0; i < 4; i += 2) {
            int row0 = rowbase + wave * 16 + q * 4 + i;
            unsigned int pk = f2bf2(acc[ct][i], acc[ct][i + 1]);
            if (row0 < N)
                H[(size_t)row0 * 128 + ct * 16 + r] = (unsigned short)pk;
            if (row0 + 1 < N)
                H[(size_t)(row0 + 1) * 128 + ct * 16 + r] = (unsigned short)(pk >> 16);
        }
    }
}

// ============================== MFMA GEMM (layers 1,2) ======================
// No A-LDS: each wave loads its own 16x128 A-tile directly from global in
// MFMA fragment order. BN scale/shift precomputed once per block into LDS
// (stats summed over the 8 contention slabs written by fused agg128).
template <int NOCT, int OST>
__global__ __launch_bounds__(256) void k_gemm_mfma(
        const unsigned short* __restrict__ X, const unsigned short* __restrict__ Wf,
        unsigned short* __restrict__ H, int N,
        const float* __restrict__ stats, const float* __restrict__ g,
        const float* __restrict__ be) {
    __shared__ unsigned short bF[NOCT * 4 * 512];
    __shared__ float2 bnss[128];
    const int tid = threadIdx.x;
    const int rowbase = blockIdx.x * 64;

    if (tid < 128) {
        const float invN = 1.0f / (float)N;
        float se = 0.f, sq = 0.f;
        #pragma unroll
        for (int s = 0; s < 8; ++s) {
            se += stats[s * 256 + tid];
            sq += stats[s * 256 + 128 + tid];
        }
        float mean = se * invN;
        float var  = fmaf(-mean, mean, sq * invN);
        float sc   = g[tid] * rsqrtf(var + BN_EPS);
        bnss[tid]  = make_float2(sc, fmaf(-mean, sc, be[tid]));
    }
    {   // stage B: NOCT col-tiles, lane-contiguous copy
        const uint4* src = (const uint4*)Wf;
        uint4* dst = (uint4*)bF;
        #pragma unroll
        for (int i = 0; i < NOCT; ++i) dst[tid + 256 * i] = src[tid + 256 * i];
    }
    __syncthreads();   // bF + bnss ready

    const int wave = tid >> 6, lane = tid & 63;
    const int r = lane & 15, q = lane >> 4;
    const int row  = rowbase + wave * 16 + r;
    const int rowc = min(row, N - 1);          // clamp: OOB rows computed, not stored

    bf16x8 afr[4];
    #pragma unroll
    for (int kt = 0; kt < 4; ++kt) {
        const int kc = kt * 32 + q * 8;
        uint4 p = *((const uint4*)(X + (size_t)rowc * 128 + kc));
        float vv[8];
        vv[0] = bflo(p.x); vv[1] = bfhi(p.x);
        vv[2] = bflo(p.y); vv[3] = bfhi(p.y);
        vv[4] = bflo(p.z); vv[5] = bfhi(p.z);
        vv[6] = bflo(p.w); vv[7] = bfhi(p.w);
        #pragma unroll
        for (int j = 0; j < 8; ++j) {
            float2 ss = bnss[kc + j];
            vv[j] = fmaxf(fmaf(vv[j], ss.x, ss.y), 0.0f);
        }
        union { unsigned int u[4]; bf16x8 v; } pk;
        pk.u[0] = f2bf2(vv[0], vv[1]);
        pk.u[1] = f2bf2(vv[2], vv[3]);
        pk.u[2] = f2bf2(vv[4], vv[5]);
        pk.u[3] = f2bf2(vv[6], vv[7]);
        afr[kt] = pk.v;
    }

    f32x4 acc[NOCT];
    #pragma unroll
    for (int ct = 0; ct < NOCT; ++ct) acc[ct] = (f32x4){0.f, 0.f, 0.f, 0.f};

    #pragma unroll
    for (int kt = 0; kt < 4; ++kt) {
        #pragma unroll
        for (int ct = 0; ct < NOCT; ++ct) {
            bf16x8 b = ((const bf16x8*)bF)[(ct * 4 + kt) * 64 + lane];
            acc[ct] = __builtin_amdgcn_mfma_f32_16x16x32_bf16(afr[kt], b, acc[ct], 0, 0, 0);
        }
    }

    // C/D: col = ct*16 + r, row = q*4 + i; pack row-pairs, split halves
    #pragma unroll
    for (int ct = 0; ct < NOCT; ++ct) {
        #pragma unroll
        for (int i = 0; i < 4; i += 2) {
            int row0 = rowbase + wave * 16 + q * 4 + i;
            unsigned int pk = f2bf2(acc[ct][i], acc[ct][i + 1]);
            if (row0 < N)
                H[(size_t)row0 * OST + ct * 16 + r] = (unsigned short)pk;
            if (row0 + 1 < N)
                H[(size_t)(row0 + 1) * OST + ct * 16 + r] = (unsigned short)(pk >> 16);
        }
    }
}

// ================ gather-based aggregate + fused BN stats ===================
// 16 lanes/node, uint4 (8ch) per lane — round-0 proven gather structure.
// Stats tail is BARRIER-FREE: lanes {l, l+16, l+32, l+48} hold the SAME 8
// channels for 4 different nodes, so 2x shfl_xor(16/32) sums the wave's 4
// nodes in-register (no LDS, no bank conflicts, no __syncthreads); lanes
// 0-15 then issue 16 atomics into the 8-slab stats. Waves exit at
// max-of-their-own-4 degrees (round-7 behavior).
__global__ __launch_bounds__(256) void k_agg128(
        const unsigned short* __restrict__ H, const int* __restrict__ rs,
        const int* __restrict__ re, const int* __restrict__ csr,
        const float* __restrict__ dinv, const float* __restrict__ b,
        unsigned short* __restrict__ outb, float* __restrict__ stats, int N) {
    const int t = threadIdx.x;
    int lane = t & 15;
    int node = blockIdx.x * 16 + (t >> 4);
    const bool valid = node < N;
    const int nodec = valid ? node : 0;
    float dd  = dinv[nodec];
    int   beg = rs[nodec];
    int   end = valid ? re[nodec] : beg;   // invalid -> empty edge loop
    uint4 hp  = ((const uint4*)(H + (size_t)nodec * 128))[lane];
    float4 bb0 = ((const float4*)b)[lane * 2];
    float4 bb1 = ((const float4*)b)[lane * 2 + 1];
    float sl = dd * dd;
    float a0 = fmaf(bflo(hp.x), sl, bb0.x), a1 = fmaf(bfhi(hp.x), sl, bb0.y);
    float a2 = fmaf(bflo(hp.y), sl, bb0.z), a3 = fmaf(bfhi(hp.y), sl, bb0.w);
    float a4 = fmaf(bflo(hp.z), sl, bb1.x), a5 = fmaf(bfhi(hp.z), sl, bb1.y);
    float a6 = fmaf(bflo(hp.w), sl, bb1.z), a7 = fmaf(bfhi(hp.w), sl, bb1.w);
    int j = beg;
    for (; j + 2 <= end; j += 2) {
        int s0 = csr[j], s1 = csr[j + 1];
        float n0 = dinv[s0] * dd, n1 = dinv[s1] * dd;
        uint4 v0 = ((const uint4*)(H + (size_t)s0 * 128))[lane];
        uint4 v1 = ((const uint4*)(H + (size_t)s1 * 128))[lane];
        a0 = fmaf(bflo(v0.x), n0, fmaf(bflo(v1.x), n1, a0));
        a1 = fmaf(bfhi(v0.x), n0, fmaf(bfhi(v1.x), n1, a1));
        a2 = fmaf(bflo(v0.y), n0, fmaf(bflo(v1.y), n1, a2));
        a3 = fmaf(bfhi(v0.y), n0, fmaf(bfhi(v1.y), n1, a3));
        a4 = fmaf(bflo(v0.z), n0, fmaf(bflo(v1.z), n1, a4));
        a5 = fmaf(bfhi(v0.z), n0, fmaf(bfhi(v1.z), n1, a5));
        a6 = fmaf(bflo(v0.w), n0, fmaf(bflo(v1.w), n1, a6));
        a7 = fmaf(bfhi(v0.w), n0, fmaf(bfhi(v1.w), n1, a7));
    }
    if (j < end) {
        int s0 = csr[j];
        float n0 = dinv[s0] * dd;
        uint4 v0 = ((const uint4*)(H + (size_t)s0 * 128))[lane];
        a0 = fmaf(bflo(v0.x), n0, a0); a1 = fmaf(bfhi(v0.x), n0, a1);
        a2 = fmaf(bflo(v0.y), n0, a2); a3 = fmaf(bfhi(v0.y), n0, a3);
        a4 = fmaf(bflo(v0.z), n0, a4); a5 = fmaf(bfhi(v0.z), n0, a5);
        a6 = fmaf(bflo(v0.w), n0, a6); a7 = fmaf(bfhi(v0.w), n0, a7);
    }
    if (valid) {
        uint4 o;
        o.x = f2bf2(a0, a1);
        o.y = f2bf2(a2, a3);
        o.z = f2bf2(a4, a5);
        o.w = f2bf2(a6, a7);
        ((uint4*)(outb + (size_t)node * 128))[lane] = o;
    } else {
        a0 = a1 = a2 = a3 = a4 = a5 = a6 = a7 = 0.f;
    }
    // ---- fused BN stats: in-wave shfl reduce + slab atomics (no barrier) ----
    float s[8] = {a0, a1, a2, a3, a4, a5, a6, a7};
    float q[8] = {a0 * a0, a1 * a1, a2 * a2, a3 * a3,
                  a4 * a4, a5 * a5, a6 * a6, a7 * a7};
    #pragma unroll
    for (int k = 0; k < 8; ++k) {
        s[k] += __shfl_xor(s[k], 16, 64);
        s[k] += __shfl_xor(s[k], 32, 64);
        q[k] += __shfl_xor(q[k], 16, 64);
        q[k] += __shfl_xor(q[k], 32, 64);
    }
    if ((t & 63) < 16) {
        const int base = (blockIdx.x & 7) * 256 + lane * 8;
        #pragma unroll
        for (int k = 0; k < 8; ++k) {
            unsafeAtomicAdd(&stats[base + k], s[k]);
            unsafeAtomicAdd(&stats[base + 128 + k], q[k]);
        }
    }
}

// 40-ch final from line-aligned stride-64 H (1 cache line per gathered row)
__global__ __launch_bounds__(256) void k_agg40(
        const unsigned short* __restrict__ H, const int* __restrict__ rs,
        const int* __restrict__ re, const int* __restrict__ csr,
        const float* __restrict__ dinv, const float* __restrict__ b,
        float* __restrict__ out, int N) {
    int lane = threadIdx.x & 15;
    int node = blockIdx.x * 16 + (threadIdx.x >> 4);
    if (node >= N || lane >= 10) return;
    float dd  = dinv[node];
    int   beg = rs[node];
    int   end = re[node];
    uint2 hp  = ((const uint2*)(H + (size_t)node * 64))[lane];
    float4 bb = ((const float4*)b)[lane];
    float  sl = dd * dd;
    float4 acc = make_float4(fmaf(bflo(hp.x), sl, bb.x), fmaf(bfhi(hp.x), sl, bb.y),
                             fmaf(bflo(hp.y), sl, bb.z), fmaf(bfhi(hp.y), sl, bb.w));
    int j = beg;
    for (; j + 2 <= end; j += 2) {
        int s0 = csr[j], s1 = csr[j + 1];
        float n0 = dinv[s0] * dd, n1 = dinv[s1] * dd;
        uint2 v0 = ((const uint2*)(H + (size_t)s0 * 64))[lane];
        uint2 v1 = ((const uint2*)(H + (size_t)s1 * 64))[lane];
        acc.x = fmaf(bflo(v0.x), n0, fmaf(bflo(v1.x), n1, acc.x));
        acc.y = fmaf(bfhi(v0.x), n0, fmaf(bfhi(v1.x), n1, acc.y));
        acc.z = fmaf(bflo(v0.y), n0, fmaf(bflo(v1.y), n1, acc.z));
        acc.w = fmaf(bfhi(v0.y), n0, fmaf(bfhi(v1.y), n1, acc.w));
    }
    if (j < end) {
        int s0 = csr[j];
        float n0 = dinv[s0] * dd;
        uint2 v0 = ((const uint2*)(H + (size_t)s0 * 64))[lane];
        acc.x = fmaf(bflo(v0.x), n0, acc.x);
        acc.y = fmaf(bfhi(v0.x), n0, acc.y);
        acc.z = fmaf(bflo(v0.y), n0, acc.z);
        acc.w = fmaf(bfhi(v0.y), n0, acc.w);
    }
    ((float4*)(out + (size_t)node * 40))[lane] = acc;
}

// ================================ launch ====================================
extern "C" void kernel_launch(void* const* d_in, const int* in_sizes, int n_in,
                              void* d_out, int out_size, void* d_ws, size_t ws_size,
                              hipStream_t stream) {
    const float* x   = (const float*)d_in[0];
    const int*   ei  = (const int*)d_in[1];      // int64 in ref -> int32 from harness
    const float* W0  = (const float*)d_in[2];
    const float* b0  = (const float*)d_in[3];
    const float* g0  = (const float*)d_in[4];
    const float* be0 = (const float*)d_in[5];
    const float* W1  = (const float*)d_in[6];
    const float* b1  = (const float*)d_in[7];
    const float* g1  = (const float*)d_in[8];
    const float* be1 = (const float*)d_in[9];
    const float* W2  = (const float*)d_in[10];
    const float* b2  = (const float*)d_in[11];
    float* out = (float*)d_out;

    const int N  = in_sizes[0] / 128;   // 170000
    const int E  = in_sizes[1] / 2;     // 1200000
    const int NB = (N + 255) >> 8;      // 665 buckets
    const int EB = (E + 8191) / 8192;   // 147 edge-chunk blocks

    // ws layout (4B units)
    float* ws   = (float*)d_ws;
    size_t Npad = ((size_t)N + 511) & ~(size_t)511;
    size_t BCAP = (size_t)NB * CAP;
    float* dinv = ws;
    int*   rs   = (int*)(ws + Npad);
    int*   re   = rs + Npad;
    int*   csr  = re + Npad;                            // BCAP
    unsigned int* ebuf = (unsigned int*)(csr + BCAP);   // BCAP
    int*   bcur = (int*)(ebuf + BCAP);                  // 1024
    float* stats0 = (float*)(bcur + 1024);              // 8 slabs x 256
    float* stats1 = stats0 + 2048;                      // 8 slabs x 256
    unsigned short* Wf = (unsigned short*)(stats1 + 2048); // 3*16384 ushort
    unsigned short* Hb = Wf + 3 * 16384;                // Npad*128 bf16
    unsigned short* Bb = Hb + Npad * 128;               // Npad*128 bf16

    int gemm_grid = (N + 63) / 64;
    int agg_grid  = (N + 15) / 16;

    // ---- dispatch 1: Wf prep + bcur/stats init (must precede bscatter) ----
    k_prepW3  <<<24, 256, 0, stream>>>(W0, W1, W2, Wf, bcur, stats0, NB);
    // ---- dispatch 2: edge scatter ----
    k_bscatter<<<EB, 256, 0, stream>>>(ei, bcur, ebuf, E, NB);
    // ---- dispatch 3: CSR finalize || layer-0 GEMM (independent roles) ----
    k_final_gemm0<<<NB + gemm_grid, 256, 0, stream>>>(ebuf, bcur, csr, rs, re,
                                                      dinv, x, Wf, Hb, N, NB);

    // ---- layer 0 aggregate (+ fused BN0 stats, barrier-free tail) ----
    k_agg128<<<agg_grid, 256, 0, stream>>>(Hb, rs, re, csr, dinv, b0, Bb,
                                           stats0, N);

    // ---- layer 1 (BN0+ReLU fused into GEMM staging); agg fuses BN1 stats ----
    k_gemm_mfma<8, 128><<<gemm_grid, 256, 0, stream>>>(Bb, Wf + 16384, Hb, N,
                                                       stats0, g0, be0);
    k_agg128<<<agg_grid, 256, 0, stream>>>(Hb, rs, re, csr, dinv, b1, Bb,
                                           stats1, N);

    // ---- layer 2 (BN1+ReLU fused) -> line-aligned 64-stride H -> 40-ch out ----
    k_gemm_mfma<3, 64><<<gemm_grid, 256, 0, stream>>>(Bb, Wf + 2 * 16384, Hb, N,
                                                      stats1, g1, be1);
    k_agg40<<<agg_grid, 256, 0, stream>>>(Hb, rs, re, csr, dinv, b2, out, N);
}

// Round 11
// 441.405 us; speedup vs baseline: 5.3490x; 5.3490x over previous
//
#include <hip/hip_runtime.h>

#define BN_EPS 1e-5f
#define CAP 3072   // per-bucket edge capacity (mean 1805, +30 sigma; guarded)

using bf16x8 = __attribute__((ext_vector_type(8))) short;
using f32x4  = __attribute__((ext_vector_type(4))) float;

__device__ __forceinline__ unsigned int f2bf(float f) {   // RTNE fp32->bf16
    unsigned int u = __float_as_uint(f);
    u += 0x7fffu + ((u >> 16) & 1u);
    return u >> 16;
}
// packed RTNE fp32x2 -> bf16x2 (bit-identical to f2bf pair)
__device__ __forceinline__ unsigned int f2bf2(float lo, float hi) {
    unsigned int r;
    asm("v_cvt_pk_bf16_f32 %0, %1, %2" : "=v"(r) : "v"(lo), "v"(hi));
    return r;
}
__device__ __forceinline__ float bflo(unsigned int u) { return __uint_as_float(u << 16); }
__device__ __forceinline__ float bfhi(unsigned int u) { return __uint_as_float(u & 0xffff0000u); }

// ========= dispatch 1: weight prep (+ bcur/stats init, own dispatch) ========
// MUST complete before k_bscatter (bcur init -> atomicAdd ordering).
// stats = 2 layers x 8 slabs x 256 floats = 4096 floats zeroed.
__global__ __launch_bounds__(256) void k_prepW3(const float* __restrict__ W0,
                                                const float* __restrict__ W1,
                                                const float* __restrict__ W2,
                                                unsigned short* __restrict__ Wf,
                                                int* __restrict__ bcur,
                                                float* __restrict__ stats, int NB) {
    int t = blockIdx.x * 256 + threadIdx.x;   // 0..6143
    if (t < NB) bcur[t] = t * CAP;            // folded k_init
    if (t < 4096) stats[t] = 0.f;             // zeroes stats0+stats1 slabs
    int wid = t >> 11;                        // 0,1,2
    int f = t & 2047;
    const float* W = (wid == 0) ? W0 : (wid == 1) ? W1 : W2;
    int C = (wid == 2) ? 40 : 128;
    int lane = f & 63, frag = f >> 6;
    int kt = frag & 3, ct = frag >> 2;
    int r = lane & 15, q = lane >> 4;
    int col = ct * 16 + r;
    int kbase = kt * 32 + q * 8;
    unsigned int v[8];
    #pragma unroll
    for (int j = 0; j < 8; ++j)
        v[j] = (col < C) ? f2bf(W[(size_t)(kbase + j) * C + col]) : 0u;
    uint4 o;
    o.x = v[0] | (v[1] << 16);
    o.y = v[2] | (v[3] << 16);
    o.z = v[4] | (v[5] << 16);
    o.w = v[6] | (v[7] << 16);
    ((uint4*)Wf)[t] = o;
}

// ===================== scatter edges into fixed buckets =====================
__global__ __launch_bounds__(256) void k_bscatter(const int* __restrict__ ei,
                                                  int* __restrict__ bcur,
                                                  unsigned int* __restrict__ ebuf,
                                                  int E, int NB) {
    __shared__ int h[768];
    __shared__ int wb[768];
    for (int i = threadIdx.x; i < 768; i += 256) h[i] = 0;
    __syncthreads();
    int base = blockIdx.x * 8192;
    int rk[32];
    #pragma unroll
    for (int it = 0; it < 32; ++it) {
        int e = base + it * 256 + threadIdx.x;
        rk[it] = (e < E) ? atomicAdd(&h[ei[E + e] >> 8], 1) : 0;
    }
    __syncthreads();
    for (int i = threadIdx.x; i < NB; i += 256) {
        int c = h[i];
        wb[i] = c ? atomicAdd(&bcur[i], c) : 0;
    }
    __syncthreads();
    #pragma unroll
    for (int it = 0; it < 32; ++it) {
        int e = base + it * 256 + threadIdx.x;
        if (e < E) {
            unsigned s = (unsigned)ei[e], d = (unsigned)ei[E + e];
            int bk = (int)(d >> 8);
            int pos = wb[bk] + rk[it];
            if (pos >= bk * CAP && pos < (bk + 1) * CAP)   // two-sided guard
                ebuf[pos] = s | ((d & 255u) << 24);
        }
    }
}

// ============ dispatch 3: CSR finalize || layer-0 GEMM (independent) ========
// blocks [0,NB): bfinal role (consumes ebuf/bcur from dispatch 2).
// blocks [NB, NB+gemm_grid): gemm0 role (consumes Wf from dispatch 1 + x).
// No intra-dispatch producer-consumer: race-free.
__global__ __launch_bounds__(256) void k_final_gemm0(
        const unsigned int* __restrict__ ebuf, const int* __restrict__ bcur,
        int* __restrict__ csr, int* __restrict__ rs, int* __restrict__ re,
        float* __restrict__ dinv,
        const float* __restrict__ X, const unsigned short* __restrict__ Wf,
        unsigned short* __restrict__ H, int N, int NB) {
    __shared__ int cnt[256];
    __shared__ int scn[256];
    __shared__ int cur[256];
    __shared__ unsigned short bF[8 * 4 * 512];
    const int t = threadIdx.x;
    if (blockIdx.x < (unsigned)NB) {
        // ---- bfinal role ----
        const int b = blockIdx.x;
        const int beg = b * CAP;
        const int cntE = min(bcur[b] - beg, CAP);
        cnt[t] = 0;
        __syncthreads();
        for (int j = t; j < cntE; j += 256)
            atomicAdd(&cnt[ebuf[beg + j] >> 24], 1);
        __syncthreads();
        int v = cnt[t];
        scn[t] = v;
        __syncthreads();
        for (int off = 1; off < 256; off <<= 1) {
            int x = (t >= off) ? scn[t - off] : 0;
            __syncthreads();
            scn[t] += x;
            __syncthreads();
        }
        int excl = scn[t] - v;
        int node = b * 256 + t;
        if (node < N) {
            rs[node]   = beg + excl;
            re[node]   = beg + excl + v;
            dinv[node] = rsqrtf((float)(1 + v));   // +1 self-loop
        }
        cur[t] = beg + excl;
        __syncthreads();
        for (int j = t; j < cntE; j += 256) {
            unsigned e = ebuf[beg + j];
            int pos = atomicAdd(&cur[e >> 24], 1);
            csr[pos] = (int)(e & 0x00FFFFFFu);
        }
        return;
    }
    // ---- gemm0 role: H[N,128] = bf16(X[N,128]_f32 @ W0) ----
    const int rowbase = (blockIdx.x - NB) * 64;
    {   // stage B: 8 col-tiles
        const uint4* src = (const uint4*)Wf;
        uint4* dst = (uint4*)bF;
        #pragma unroll
        for (int i = 0; i < 8; ++i) dst[t + 256 * i] = src[t + 256 * i];
    }
    __syncthreads();

    const int wave = t >> 6, lane = t & 63;
    const int r = lane & 15, q = lane >> 4;
    const int row  = rowbase + wave * 16 + r;
    const int rowc = min(row, N - 1);          // clamp: OOB rows computed, not stored

    bf16x8 afr[4];
    #pragma unroll
    for (int kt = 0; kt < 4; ++kt) {
        const int kc = kt * 32 + q * 8;
        const float4* xp = (const float4*)(X + (size_t)rowc * 128 + kc);
        float4 p0 = xp[0], p1 = xp[1];
        union { unsigned int u[4]; bf16x8 v; } pk;
        pk.u[0] = f2bf2(p0.x, p0.y);
        pk.u[1] = f2bf2(p0.z, p0.w);
        pk.u[2] = f2bf2(p1.x, p1.y);
        pk.u[3] = f2bf2(p1.z, p1.w);
        afr[kt] = pk.v;
    }

    f32x4 acc[8];
    #pragma unroll
    for (int ct = 0; ct < 8; ++ct) acc[ct] = (f32x4){0.f, 0.f, 0.f, 0.f};
    #pragma unroll
    for (int kt = 0; kt < 4; ++kt) {
        #pragma unroll
        for (int ct = 0; ct < 8; ++ct) {
            bf16x8 b = ((const bf16x8*)bF)[(ct * 4 + kt) * 64 + lane];
            acc[ct] = __builtin_amdgcn_mfma_f32_16x16x32_bf16(afr[kt], b, acc[ct], 0, 0, 0);
        }
    }
    #pragma unroll
    for (int ct = 0; ct < 8; ++ct) {
        #pragma unroll
        for (int i = 0; i < 4; i += 2) {
            int row0 = rowbase + wave * 16 + q * 4 + i;
            unsigned int pk = f2bf2(acc[ct][i], acc[ct][i + 1]);
            if (row0 < N)
                H[(size_t)row0 * 128 + ct * 16 + r] = (unsigned short)pk;
            if (row0 + 1 < N)
                H[(size_t)(row0 + 1) * 128 + ct * 16 + r] = (unsigned short)(pk >> 16);
        }
    }
}

// ============================== MFMA GEMM (layers 1,2) ======================
// No A-LDS: each wave loads its own 16x128 A-tile directly from global in
// MFMA fragment order. BN scale/shift precomputed once per block into LDS
// (stats summed over the 8 contention slabs written by fused agg128).
template <int NOCT, int OST>
__global__ __launch_bounds__(256) void k_gemm_mfma(
        const unsigned short* __restrict__ X, const unsigned short* __restrict__ Wf,
        unsigned short* __restrict__ H, int N,
        const float* __restrict__ stats, const float* __restrict__ g,
        const float* __restrict__ be) {
    __shared__ unsigned short bF[NOCT * 4 * 512];
    __shared__ float2 bnss[128];
    const int tid = threadIdx.x;
    const int rowbase = blockIdx.x * 64;

    if (tid < 128) {
        const float invN = 1.0f / (float)N;
        float se = 0.f, sq = 0.f;
        #pragma unroll
        for (int s = 0; s < 8; ++s) {
            se += stats[s * 256 + tid];
            sq += stats[s * 256 + 128 + tid];
        }
        float mean = se * invN;
        float var  = fmaf(-mean, mean, sq * invN);
        float sc   = g[tid] * rsqrtf(var + BN_EPS);
        bnss[tid]  = make_float2(sc, fmaf(-mean, sc, be[tid]));
    }
    {   // stage B: NOCT col-tiles, lane-contiguous copy
        const uint4* src = (const uint4*)Wf;
        uint4* dst = (uint4*)bF;
        #pragma unroll
        for (int i = 0; i < NOCT; ++i) dst[tid + 256 * i] = src[tid + 256 * i];
    }
    __syncthreads();   // bF + bnss ready

    const int wave = tid >> 6, lane = tid & 63;
    const int r = lane & 15, q = lane >> 4;
    const int row  = rowbase + wave * 16 + r;
    const int rowc = min(row, N - 1);          // clamp: OOB rows computed, not stored

    bf16x8 afr[4];
    #pragma unroll
    for (int kt = 0; kt < 4; ++kt) {
        const int kc = kt * 32 + q * 8;
        uint4 p = *((const uint4*)(X + (size_t)rowc * 128 + kc));
        float vv[8];
        vv[0] = bflo(p.x); vv[1] = bfhi(p.x);
        vv[2] = bflo(p.y); vv[3] = bfhi(p.y);
        vv[4] = bflo(p.z); vv[5] = bfhi(p.z);
        vv[6] = bflo(p.w); vv[7] = bfhi(p.w);
        #pragma unroll
        for (int j = 0; j < 8; ++j) {
            float2 ss = bnss[kc + j];
            vv[j] = fmaxf(fmaf(vv[j], ss.x, ss.y), 0.0f);
        }
        union { unsigned int u[4]; bf16x8 v; } pk;
        pk.u[0] = f2bf2(vv[0], vv[1]);
        pk.u[1] = f2bf2(vv[2], vv[3]);
        pk.u[2] = f2bf2(vv[4], vv[5]);
        pk.u[3] = f2bf2(vv[6], vv[7]);
        afr[kt] = pk.v;
    }

    f32x4 acc[NOCT];
    #pragma unroll
    for (int ct = 0; ct < NOCT; ++ct) acc[ct] = (f32x4){0.f, 0.f, 0.f, 0.f};

    #pragma unroll
    for (int kt = 0; kt < 4; ++kt) {
        #pragma unroll
        for (int ct = 0; ct < NOCT; ++ct) {
            bf16x8 b = ((const bf16x8*)bF)[(ct * 4 + kt) * 64 + lane];
            acc[ct] = __builtin_amdgcn_mfma_f32_16x16x32_bf16(afr[kt], b, acc[ct], 0, 0, 0);
        }
    }

    // C/D: col = ct*16 + r, row = q*4 + i; pack row-pairs, split halves
    #pragma unroll
    for (int ct = 0; ct < NOCT; ++ct) {
        #pragma unroll
        for (int i = 0; i < 4; i += 2) {
            int row0 = rowbase + wave * 16 + q * 4 + i;
            unsigned int pk = f2bf2(acc[ct][i], acc[ct][i + 1]);
            if (row0 < N)
                H[(size_t)row0 * OST + ct * 16 + r] = (unsigned short)pk;
            if (row0 + 1 < N)
                H[(size_t)(row0 + 1) * OST + ct * 16 + r] = (unsigned short)(pk >> 16);
        }
    }
}

// ================ gather-based aggregate + fused BN stats ===================
// 16 lanes/node, uint4 (8ch) per lane — round-8 proven form with ONE fix:
// LDS inner dim padded 128 -> 132 so the stats-tail write (stride 8 floats
// per lane) spreads over 16 banks instead of 4 (16-way -> ~4-way conflict).
// Atomics stay one-per-thread at consecutive addresses (wave-coalesced).
__global__ __launch_bounds__(256) void k_agg128(
        const unsigned short* __restrict__ H, const int* __restrict__ rs,
        const int* __restrict__ re, const int* __restrict__ csr,
        const float* __restrict__ dinv, const float* __restrict__ b,
        unsigned short* __restrict__ outb, float* __restrict__ stats, int N) {
    __shared__ float red[2][16][132];   // +4 pad: bank spread for stride-8 writes
    const int t = threadIdx.x;
    int lane = t & 15;
    int node = blockIdx.x * 16 + (t >> 4);
    const bool valid = node < N;
    const int nodec = valid ? node : 0;
    float dd  = dinv[nodec];
    int   beg = rs[nodec];
    int   end = valid ? re[nodec] : beg;   // invalid -> empty edge loop
    uint4 hp  = ((const uint4*)(H + (size_t)nodec * 128))[lane];
    float4 bb0 = ((const float4*)b)[lane * 2];
    float4 bb1 = ((const float4*)b)[lane * 2 + 1];
    float sl = dd * dd;
    float a0 = fmaf(bflo(hp.x), sl, bb0.x), a1 = fmaf(bfhi(hp.x), sl, bb0.y);
    float a2 = fmaf(bflo(hp.y), sl, bb0.z), a3 = fmaf(bfhi(hp.y), sl, bb0.w);
    float a4 = fmaf(bflo(hp.z), sl, bb1.x), a5 = fmaf(bfhi(hp.z), sl, bb1.y);
    float a6 = fmaf(bflo(hp.w), sl, bb1.z), a7 = fmaf(bfhi(hp.w), sl, bb1.w);
    int j = beg;
    for (; j + 2 <= end; j += 2) {
        int s0 = csr[j], s1 = csr[j + 1];
        float n0 = dinv[s0] * dd, n1 = dinv[s1] * dd;
        uint4 v0 = ((const uint4*)(H + (size_t)s0 * 128))[lane];
        uint4 v1 = ((const uint4*)(H + (size_t)s1 * 128))[lane];
        a0 = fmaf(bflo(v0.x), n0, fmaf(bflo(v1.x), n1, a0));
        a1 = fmaf(bfhi(v0.x), n0, fmaf(bfhi(v1.x), n1, a1));
        a2 = fmaf(bflo(v0.y), n0, fmaf(bflo(v1.y), n1, a2));
        a3 = fmaf(bfhi(v0.y), n0, fmaf(bfhi(v1.y), n1, a3));
        a4 = fmaf(bflo(v0.z), n0, fmaf(bflo(v1.z), n1, a4));
        a5 = fmaf(bfhi(v0.z), n0, fmaf(bfhi(v1.z), n1, a5));
        a6 = fmaf(bflo(v0.w), n0, fmaf(bflo(v1.w), n1, a6));
        a7 = fmaf(bfhi(v0.w), n0, fmaf(bfhi(v1.w), n1, a7));
    }
    if (j < end) {
        int s0 = csr[j];
        float n0 = dinv[s0] * dd;
        uint4 v0 = ((const uint4*)(H + (size_t)s0 * 128))[lane];
        a0 = fmaf(bflo(v0.x), n0, a0); a1 = fmaf(bfhi(v0.x), n0, a1);
        a2 = fmaf(bflo(v0.y), n0, a2); a3 = fmaf(bfhi(v0.y), n0, a3);
        a4 = fmaf(bflo(v0.z), n0, a4); a5 = fmaf(bfhi(v0.z), n0, a5);
        a6 = fmaf(bflo(v0.w), n0, a6); a7 = fmaf(bfhi(v0.w), n0, a7);
    }
    if (valid) {
        uint4 o;
        o.x = f2bf2(a0, a1);
        o.y = f2bf2(a2, a3);
        o.z = f2bf2(a4, a5);
        o.w = f2bf2(a6, a7);
        ((uint4*)(outb + (size_t)node * 128))[lane] = o;
    } else {
        a0 = a1 = a2 = a3 = a4 = a5 = a6 = a7 = 0.f;
    }
    // ---- fused BN stats: per-node partials -> padded LDS -> slab atomics ----
    const int grp = t >> 4, cb = lane * 8;
    red[0][grp][cb + 0] = a0; red[1][grp][cb + 0] = a0 * a0;
    red[0][grp][cb + 1] = a1; red[1][grp][cb + 1] = a1 * a1;
    red[0][grp][cb + 2] = a2; red[1][grp][cb + 2] = a2 * a2;
    red[0][grp][cb + 3] = a3; red[1][grp][cb + 3] = a3 * a3;
    red[0][grp][cb + 4] = a4; red[1][grp][cb + 4] = a4 * a4;
    red[0][grp][cb + 5] = a5; red[1][grp][cb + 5] = a5 * a5;
    red[0][grp][cb + 6] = a6; red[1][grp][cb + 6] = a6 * a6;
    red[0][grp][cb + 7] = a7; red[1][grp][cb + 7] = a7 * a7;
    __syncthreads();
    const int slab = blockIdx.x & 7;
    const int rot  = (blockIdx.x >> 3) << 2;   // stagger channel order
    if (t < 128) {
        int c = (t + rot) & 127;
        float acc = 0.f;
        #pragma unroll
        for (int g = 0; g < 16; ++g) acc += red[0][g][c];
        unsafeAtomicAdd(&stats[slab * 256 + c], acc);
    } else {
        int c = ((t - 128) + rot) & 127;
        float acc = 0.f;
        #pragma unroll
        for (int g = 0; g < 16; ++g) acc += red[1][g][c];
        unsafeAtomicAdd(&stats[slab * 256 + 128 + c], acc);
    }
}

// 40-ch final from line-aligned stride-64 H (1 cache line per gathered row)
__global__ __launch_bounds__(256) void k_agg40(
        const unsigned short* __restrict__ H, const int* __restrict__ rs,
        const int* __restrict__ re, const int* __restrict__ csr,
        const float* __restrict__ dinv, const float* __restrict__ b,
        float* __restrict__ out, int N) {
    int lane = threadIdx.x & 15;
    int node = blockIdx.x * 16 + (threadIdx.x >> 4);
    if (node >= N || lane >= 10) return;
    float dd  = dinv[node];
    int   beg = rs[node];
    int   end = re[node];
    uint2 hp  = ((const uint2*)(H + (size_t)node * 64))[lane];
    float4 bb = ((const float4*)b)[lane];
    float  sl = dd * dd;
    float4 acc = make_float4(fmaf(bflo(hp.x), sl, bb.x), fmaf(bfhi(hp.x), sl, bb.y),
                             fmaf(bflo(hp.y), sl, bb.z), fmaf(bfhi(hp.y), sl, bb.w));
    int j = beg;
    for (; j + 2 <= end; j += 2) {
        int s0 = csr[j], s1 = csr[j + 1];
        float n0 = dinv[s0] * dd, n1 = dinv[s1] * dd;
        uint2 v0 = ((const uint2*)(H + (size_t)s0 * 64))[lane];
        uint2 v1 = ((const uint2*)(H + (size_t)s1 * 64))[lane];
        acc.x = fmaf(bflo(v0.x), n0, fmaf(bflo(v1.x), n1, acc.x));
        acc.y = fmaf(bfhi(v0.x), n0, fmaf(bfhi(v1.x), n1, acc.y));
        acc.z = fmaf(bflo(v0.y), n0, fmaf(bflo(v1.y), n1, acc.z));
        acc.w = fmaf(bfhi(v0.y), n0, fmaf(bfhi(v1.y), n1, acc.w));
    }
    if (j < end) {
        int s0 = csr[j];
        float n0 = dinv[s0] * dd;
        uint2 v0 = ((const uint2*)(H + (size_t)s0 * 64))[lane];
        acc.x = fmaf(bflo(v0.x), n0, acc.x);
        acc.y = fmaf(bfhi(v0.x), n0, acc.y);
        acc.z = fmaf(bflo(v0.y), n0, acc.z);
        acc.w = fmaf(bfhi(v0.y), n0, acc.w);
    }
    ((float4*)(out + (size_t)node * 40))[lane] = acc;
}

// ================================ launch ====================================
extern "C" void kernel_launch(void* const* d_in, const int* in_sizes, int n_in,
                              void* d_out, int out_size, void* d_ws, size_t ws_size,
                              hipStream_t stream) {
    const float* x   = (const float*)d_in[0];
    const int*   ei  = (const int*)d_in[1];      // int64 in ref -> int32 from harness
    const float* W0  = (const float*)d_in[2];
    const float* b0  = (const float*)d_in[3];
    const float* g0  = (const float*)d_in[4];
    const float* be0 = (const float*)d_in[5];
    const float* W1  = (const float*)d_in[6];
    const float* b1  = (const float*)d_in[7];
    const float* g1  = (const float*)d_in[8];
    const float* be1 = (const float*)d_in[9];
    const float* W2  = (const float*)d_in[10];
    const float* b2  = (const float*)d_in[11];
    float* out = (float*)d_out;

    const int N  = in_sizes[0] / 128;   // 170000
    const int E  = in_sizes[1] / 2;     // 1200000
    const int NB = (N + 255) >> 8;      // 665 buckets
    const int EB = (E + 8191) / 8192;   // 147 edge-chunk blocks

    // ws layout (4B units)
    float* ws   = (float*)d_ws;
    size_t Npad = ((size_t)N + 511) & ~(size_t)511;
    size_t BCAP = (size_t)NB * CAP;
    float* dinv = ws;
    int*   rs   = (int*)(ws + Npad);
    int*   re   = rs + Npad;
    int*   csr  = re + Npad;                            // BCAP
    unsigned int* ebuf = (unsigned int*)(csr + BCAP);   // BCAP
    int*   bcur = (int*)(ebuf + BCAP);                  // 1024
    float* stats0 = (float*)(bcur + 1024);              // 8 slabs x 256
    float* stats1 = stats0 + 2048;                      // 8 slabs x 256
    unsigned short* Wf = (unsigned short*)(stats1 + 2048); // 3*16384 ushort
    unsigned short* Hb = Wf + 3 * 16384;                // Npad*128 bf16
    unsigned short* Bb = Hb + Npad * 128;               // Npad*128 bf16

    int gemm_grid = (N + 63) / 64;
    int agg_grid  = (N + 15) / 16;

    // ---- dispatch 1: Wf prep + bcur/stats init (must precede bscatter) ----
    k_prepW3  <<<24, 256, 0, stream>>>(W0, W1, W2, Wf, bcur, stats0, NB);
    // ---- dispatch 2: edge scatter ----
    k_bscatter<<<EB, 256, 0, stream>>>(ei, bcur, ebuf, E, NB);
    // ---- dispatch 3: CSR finalize || layer-0 GEMM (independent roles) ----
    k_final_gemm0<<<NB + gemm_grid, 256, 0, stream>>>(ebuf, bcur, csr, rs, re,
                                                      dinv, x, Wf, Hb, N, NB);

    // ---- layer 0 aggregate (+ fused BN0 stats) ----
    k_agg128<<<agg_grid, 256, 0, stream>>>(Hb, rs, re, csr, dinv, b0, Bb,
                                           stats0, N);

    // ---- layer 1 (BN0+ReLU fused into GEMM staging); agg fuses BN1 stats ----
    k_gemm_mfma<8, 128><<<gemm_grid, 256, 0, stream>>>(Bb, Wf + 16384, Hb, N,
                                                       stats0, g0, be0);
    k_agg128<<<agg_grid, 256, 0, stream>>>(Hb, rs, re, csr, dinv, b1, Bb,
                                           stats1, N);

    // ---- layer 2 (BN1+ReLU fused) -> line-aligned 64-stride H -> 40-ch out ----
    k_gemm_mfma<3, 64><<<gemm_grid, 256, 0, stream>>>(Bb, Wf + 2 * 16384, Hb, N,
                                                      stats1, g1, be1);
    k_agg40<<<agg_grid, 256, 0, stream>>>(Hb, rs, re, csr, dinv, b2, out, N);
}

// Round 13
// 436.064 us; speedup vs baseline: 5.4145x; 1.0122x over previous
//
#include <hip/hip_runtime.h>

#define BN_EPS 1e-5f
#define CAP 3072   // per-bucket edge capacity (mean 1805, +30 sigma; guarded)
#define CNT_STRIDE 16384   // per-launch block-counter array (>= agg_grid)

using bf16x8 = __attribute__((ext_vector_type(8))) short;
using f32x4  = __attribute__((ext_vector_type(4))) float;

__device__ __forceinline__ unsigned int f2bf(float f) {   // RTNE fp32->bf16
    unsigned int u = __float_as_uint(f);
    u += 0x7fffu + ((u >> 16) & 1u);
    return u >> 16;
}
// packed RTNE fp32x2 -> bf16x2 (bit-identical to f2bf pair)
__device__ __forceinline__ unsigned int f2bf2(float lo, float hi) {
    unsigned int r;
    asm("v_cvt_pk_bf16_f32 %0, %1, %2" : "=v"(r) : "v"(lo), "v"(hi));
    return r;
}
__device__ __forceinline__ float bflo(unsigned int u) { return __uint_as_float(u << 16); }
__device__ __forceinline__ float bfhi(unsigned int u) { return __uint_as_float(u & 0xffff0000u); }

// ========= dispatch 1: weight prep (+ bcur/stats/cnt init, own dispatch) ====
// MUST complete before k_bscatter (bcur init -> atomicAdd ordering).
__global__ __launch_bounds__(256) void k_prepW3(const float* __restrict__ W0,
                                                const float* __restrict__ W1,
                                                const float* __restrict__ W2,
                                                unsigned short* __restrict__ Wf,
                                                int* __restrict__ bcur,
                                                float* __restrict__ stats,
                                                int* __restrict__ cnt, int NB) {
    int t = blockIdx.x * 256 + threadIdx.x;   // 0..6143
    if (t < NB) bcur[t] = t * CAP;            // folded k_init
    if (t < 4096) stats[t] = 0.f;             // zeroes stats0+stats1 slabs
    for (int z = t; z < 2 * CNT_STRIDE; z += 6144) cnt[z] = 0;  // flush counters
    int wid = t >> 11;                        // 0,1,2
    int f = t & 2047;
    const float* W = (wid == 0) ? W0 : (wid == 1) ? W1 : W2;
    int C = (wid == 2) ? 40 : 128;
    int lane = f & 63, frag = f >> 6;
    int kt = frag & 3, ct = frag >> 2;
    int r = lane & 15, q = lane >> 4;
    int col = ct * 16 + r;
    int kbase = kt * 32 + q * 8;
    unsigned int v[8];
    #pragma unroll
    for (int j = 0; j < 8; ++j)
        v[j] = (col < C) ? f2bf(W[(size_t)(kbase + j) * C + col]) : 0u;
    uint4 o;
    o.x = v[0] | (v[1] << 16);
    o.y = v[2] | (v[3] << 16);
    o.z = v[4] | (v[5] << 16);
    o.w = v[6] | (v[7] << 16);
    ((uint4*)Wf)[t] = o;
}

// ===================== scatter edges into fixed buckets =====================
__global__ __launch_bounds__(256) void k_bscatter(const int* __restrict__ ei,
                                                  int* __restrict__ bcur,
                                                  unsigned int* __restrict__ ebuf,
                                                  int E, int NB) {
    __shared__ int h[768];
    __shared__ int wb[768];
    for (int i = threadIdx.x; i < 768; i += 256) h[i] = 0;
    __syncthreads();
    int base = blockIdx.x * 8192;
    int rk[32];
    #pragma unroll
    for (int it = 0; it < 32; ++it) {
        int e = base + it * 256 + threadIdx.x;
        rk[it] = (e < E) ? atomicAdd(&h[ei[E + e] >> 8], 1) : 0;
    }
    __syncthreads();
    for (int i = threadIdx.x; i < NB; i += 256) {
        int c = h[i];
        wb[i] = c ? atomicAdd(&bcur[i], c) : 0;
    }
    __syncthreads();
    #pragma unroll
    for (int it = 0; it < 32; ++it) {
        int e = base + it * 256 + threadIdx.x;
        if (e < E) {
            unsigned s = (unsigned)ei[e], d = (unsigned)ei[E + e];
            int bk = (int)(d >> 8);
            int pos = wb[bk] + rk[it];
            if (pos >= bk * CAP && pos < (bk + 1) * CAP)   // two-sided guard
                ebuf[pos] = s | ((d & 255u) << 24);
        }
    }
}

// ============ dispatch 3: CSR finalize || layer-0 GEMM (independent) ========
// blocks [0,NB): bfinal role (consumes ebuf/bcur from dispatch 2).
// blocks [NB, NB+gemm_grid): gemm0 role (consumes Wf from dispatch 1 + x).
// No intra-dispatch producer-consumer: race-free.
__global__ __launch_bounds__(256) void k_final_gemm0(
        const unsigned int* __restrict__ ebuf, const int* __restrict__ bcur,
        int* __restrict__ csr, int* __restrict__ rs, int* __restrict__ re,
        float* __restrict__ dinv,
        const float* __restrict__ X, const unsigned short* __restrict__ Wf,
        unsigned short* __restrict__ H, int N, int NB) {
    __shared__ int cnt[256];
    __shared__ int scn[256];
    __shared__ int cur[256];
    __shared__ unsigned short bF[8 * 4 * 512];
    const int t = threadIdx.x;
    if (blockIdx.x < (unsigned)NB) {
        // ---- bfinal role ----
        const int b = blockIdx.x;
        const int beg = b * CAP;
        const int cntE = min(bcur[b] - beg, CAP);
        cnt[t] = 0;
        __syncthreads();
        for (int j = t; j < cntE; j += 256)
            atomicAdd(&cnt[ebuf[beg + j] >> 24], 1);
        __syncthreads();
        int v = cnt[t];
        scn[t] = v;
        __syncthreads();
        for (int off = 1; off < 256; off <<= 1) {
            int x = (t >= off) ? scn[t - off] : 0;
            __syncthreads();
            scn[t] += x;
            __syncthreads();
        }
        int excl = scn[t] - v;
        int node = b * 256 + t;
        if (node < N) {
            rs[node]   = beg + excl;
            re[node]   = beg + excl + v;
            dinv[node] = rsqrtf((float)(1 + v));   // +1 self-loop
        }
        cur[t] = beg + excl;
        __syncthreads();
        for (int j = t; j < cntE; j += 256) {
            unsigned e = ebuf[beg + j];
            int pos = atomicAdd(&cur[e >> 24], 1);
            csr[pos] = (int)(e & 0x00FFFFFFu);
        }
        return;
    }
    // ---- gemm0 role: H[N,128] = bf16(X[N,128]_f32 @ W0) ----
    const int rowbase = (blockIdx.x - NB) * 64;
    {   // stage B: 8 col-tiles
        const uint4* src = (const uint4*)Wf;
        uint4* dst = (uint4*)bF;
        #pragma unroll
        for (int i = 0; i < 8; ++i) dst[t + 256 * i] = src[t + 256 * i];
    }
    __syncthreads();

    const int wave = t >> 6, lane = t & 63;
    const int r = lane & 15, q = lane >> 4;
    const int row  = rowbase + wave * 16 + r;
    const int rowc = min(row, N - 1);          // clamp: OOB rows computed, not stored

    bf16x8 afr[4];
    #pragma unroll
    for (int kt = 0; kt < 4; ++kt) {
        const int kc = kt * 32 + q * 8;
        const float4* xp = (const float4*)(X + (size_t)rowc * 128 + kc);
        float4 p0 = xp[0], p1 = xp[1];
        union { unsigned int u[4]; bf16x8 v; } pk;
        pk.u[0] = f2bf2(p0.x, p0.y);
        pk.u[1] = f2bf2(p0.z, p0.w);
        pk.u[2] = f2bf2(p1.x, p1.y);
        pk.u[3] = f2bf2(p1.z, p1.w);
        afr[kt] = pk.v;
    }

    f32x4 acc[8];
    #pragma unroll
    for (int ct = 0; ct < 8; ++ct) acc[ct] = (f32x4){0.f, 0.f, 0.f, 0.f};
    #pragma unroll
    for (int kt = 0; kt < 4; ++kt) {
        #pragma unroll
        for (int ct = 0; ct < 8; ++ct) {
            bf16x8 b = ((const bf16x8*)bF)[(ct * 4 + kt) * 64 + lane];
            acc[ct] = __builtin_amdgcn_mfma_f32_16x16x32_bf16(afr[kt], b, acc[ct], 0, 0, 0);
        }
    }
    #pragma unroll
    for (int ct = 0; ct < 8; ++ct) {
        #pragma unroll
        for (int i = 0; i < 4; i += 2) {
            int row0 = rowbase + wave * 16 + q * 4 + i;
            unsigned int pk = f2bf2(acc[ct][i], acc[ct][i + 1]);
            if (row0 < N)
                H[(size_t)row0 * 128 + ct * 16 + r] = (unsigned short)pk;
            if (row0 + 1 < N)
                H[(size_t)(row0 + 1) * 128 + ct * 16 + r] = (unsigned short)(pk >> 16);
        }
    }
}

// ============================== MFMA GEMM (layers 1,2) ======================
// No A-LDS: each wave loads its own 16x128 A-tile directly from global in
// MFMA fragment order. BN scale/shift precomputed once per block into LDS
// (stats summed over the 8 contention slabs written by fused agg128).
template <int NOCT, int OST>
__global__ __launch_bounds__(256) void k_gemm_mfma(
        const unsigned short* __restrict__ X, const unsigned short* __restrict__ Wf,
        unsigned short* __restrict__ H, int N,
        const float* __restrict__ stats, const float* __restrict__ g,
        const float* __restrict__ be) {
    __shared__ unsigned short bF[NOCT * 4 * 512];
    __shared__ float2 bnss[128];
    const int tid = threadIdx.x;
    const int rowbase = blockIdx.x * 64;

    if (tid < 128) {
        const float invN = 1.0f / (float)N;
        float se = 0.f, sq = 0.f;
        #pragma unroll
        for (int s = 0; s < 8; ++s) {
            se += stats[s * 256 + tid];
            sq += stats[s * 256 + 128 + tid];
        }
        float mean = se * invN;
        float var  = fmaf(-mean, mean, sq * invN);
        float sc   = g[tid] * rsqrtf(var + BN_EPS);
        bnss[tid]  = make_float2(sc, fmaf(-mean, sc, be[tid]));
    }
    {   // stage B: NOCT col-tiles, lane-contiguous copy
        const uint4* src = (const uint4*)Wf;
        uint4* dst = (uint4*)bF;
        #pragma unroll
        for (int i = 0; i < NOCT; ++i) dst[tid + 256 * i] = src[tid + 256 * i];
    }
    __syncthreads();   // bF + bnss ready

    const int wave = tid >> 6, lane = tid & 63;
    const int r = lane & 15, q = lane >> 4;
    const int row  = rowbase + wave * 16 + r;
    const int rowc = min(row, N - 1);          // clamp: OOB rows computed, not stored

    bf16x8 afr[4];
    #pragma unroll
    for (int kt = 0; kt < 4; ++kt) {
        const int kc = kt * 32 + q * 8;
        uint4 p = *((const uint4*)(X + (size_t)rowc * 128 + kc));
        float vv[8];
        vv[0] = bflo(p.x); vv[1] = bfhi(p.x);
        vv[2] = bflo(p.y); vv[3] = bfhi(p.y);
        vv[4] = bflo(p.z); vv[5] = bfhi(p.z);
        vv[6] = bflo(p.w); vv[7] = bfhi(p.w);
        #pragma unroll
        for (int j = 0; j < 8; ++j) {
            float2 ss = bnss[kc + j];
            vv[j] = fmaxf(fmaf(vv[j], ss.x, ss.y), 0.0f);
        }
        union { unsigned int u[4]; bf16x8 v; } pk;
        pk.u[0] = f2bf2(vv[0], vv[1]);
        pk.u[1] = f2bf2(vv[2], vv[3]);
        pk.u[2] = f2bf2(vv[4], vv[5]);
        pk.u[3] = f2bf2(vv[6], vv[7]);
        afr[kt] = pk.v;
    }

    f32x4 acc[NOCT];
    #pragma unroll
    for (int ct = 0; ct < NOCT; ++ct) acc[ct] = (f32x4){0.f, 0.f, 0.f, 0.f};

    #pragma unroll
    for (int kt = 0; kt < 4; ++kt) {
        #pragma unroll
        for (int ct = 0; ct < NOCT; ++ct) {
            bf16x8 b = ((const bf16x8*)bF)[(ct * 4 + kt) * 64 + lane];
            acc[ct] = __builtin_amdgcn_mfma_f32_16x16x32_bf16(afr[kt], b, acc[ct], 0, 0, 0);
        }
    }

    // C/D: col = ct*16 + r, row = q*4 + i; pack row-pairs, split halves
    #pragma unroll
    for (int ct = 0; ct < NOCT; ++ct) {
        #pragma unroll
        for (int i = 0; i < 4; i += 2) {
            int row0 = rowbase + wave * 16 + q * 4 + i;
            unsigned int pk = f2bf2(acc[ct][i], acc[ct][i + 1]);
            if (row0 < N)
                H[(size_t)row0 * OST + ct * 16 + r] = (unsigned short)pk;
            if (row0 + 1 < N)
                H[(size_t)(row0 + 1) * OST + ct * 16 + r] = (unsigned short)(pk >> 16);
        }
    }
}

// ================ gather-based aggregate + fused BN stats ===================
// 16 lanes/node, uint4 (8ch) per lane — round-0 gather structure. Stats tail
// is BARRIER-FREE last-wave-flush: each wave shfl-reduces its own 4 nodes,
// writes 256 partials to a wave-private 1KB LDS region (plain ds_write, wave-
// ordered), fences, bumps a per-block global counter; the 4th wave sums the
// regions and issues ONE coalesced 256-atomic batch (round-8 atomic pattern).
// Waves exit at max-of-their-own-4 degrees (round-7 lifetime).
__global__ __launch_bounds__(256) void k_agg128(
        const unsigned short* __restrict__ H, const int* __restrict__ rs,
        const int* __restrict__ re, const int* __restrict__ csr,
        const float* __restrict__ dinv, const float* __restrict__ b,
        unsigned short* __restrict__ outb, float* __restrict__ stats,
        int* __restrict__ cnt, int N) {
    __shared__ float wred[4][256];   // per-wave 1KB partial region
    const int t = threadIdx.x;
    int lane = t & 15;
    int node = blockIdx.x * 16 + (t >> 4);
    const bool valid = node < N;
    const int nodec = valid ? node : 0;
    float dd  = dinv[nodec];
    int   beg = rs[nodec];
    int   end = valid ? re[nodec] : beg;   // invalid -> empty edge loop
    uint4 hp  = ((const uint4*)(H + (size_t)nodec * 128))[lane];
    float4 bb0 = ((const float4*)b)[lane * 2];
    float4 bb1 = ((const float4*)b)[lane * 2 + 1];
    float sl = dd * dd;
    float a0 = fmaf(bflo(hp.x), sl, bb0.x), a1 = fmaf(bfhi(hp.x), sl, bb0.y);
    float a2 = fmaf(bflo(hp.y), sl, bb0.z), a3 = fmaf(bfhi(hp.y), sl, bb0.w);
    float a4 = fmaf(bflo(hp.z), sl, bb1.x), a5 = fmaf(bfhi(hp.z), sl, bb1.y);
    float a6 = fmaf(bflo(hp.w), sl, bb1.z), a7 = fmaf(bfhi(hp.w), sl, bb1.w);
    int j = beg;
    for (; j + 2 <= end; j += 2) {
        int s0 = csr[j], s1 = csr[j + 1];
        float n0 = dinv[s0] * dd, n1 = dinv[s1] * dd;
        uint4 v0 = ((const uint4*)(H + (size_t)s0 * 128))[lane];
        uint4 v1 = ((const uint4*)(H + (size_t)s1 * 128))[lane];
        a0 = fmaf(bflo(v0.x), n0, fmaf(bflo(v1.x), n1, a0));
        a1 = fmaf(bfhi(v0.x), n0, fmaf(bfhi(v1.x), n1, a1));
        a2 = fmaf(bflo(v0.y), n0, fmaf(bflo(v1.y), n1, a2));
        a3 = fmaf(bfhi(v0.y), n0, fmaf(bfhi(v1.y), n1, a3));
        a4 = fmaf(bflo(v0.z), n0, fmaf(bflo(v1.z), n1, a4));
        a5 = fmaf(bfhi(v0.z), n0, fmaf(bfhi(v1.z), n1, a5));
        a6 = fmaf(bflo(v0.w), n0, fmaf(bflo(v1.w), n1, a6));
        a7 = fmaf(bfhi(v0.w), n0, fmaf(bfhi(v1.w), n1, a7));
    }
    if (j < end) {
        int s0 = csr[j];
        float n0 = dinv[s0] * dd;
        uint4 v0 = ((const uint4*)(H + (size_t)s0 * 128))[lane];
        a0 = fmaf(bflo(v0.x), n0, a0); a1 = fmaf(bfhi(v0.x), n0, a1);
        a2 = fmaf(bflo(v0.y), n0, a2); a3 = fmaf(bfhi(v0.y), n0, a3);
        a4 = fmaf(bflo(v0.z), n0, a4); a5 = fmaf(bfhi(v0.z), n0, a5);
        a6 = fmaf(bflo(v0.w), n0, a6); a7 = fmaf(bfhi(v0.w), n0, a7);
    }
    if (valid) {
        uint4 o;
        o.x = f2bf2(a0, a1);
        o.y = f2bf2(a2, a3);
        o.z = f2bf2(a4, a5);
        o.w = f2bf2(a6, a7);
        ((uint4*)(outb + (size_t)node * 128))[lane] = o;
    } else {
        a0 = a1 = a2 = a3 = a4 = a5 = a6 = a7 = 0.f;
    }
    // ---- fused BN stats: wave shfl-reduce -> LDS region -> last-wave flush ----
    float s[8] = {a0, a1, a2, a3, a4, a5, a6, a7};
    float q[8] = {a0 * a0, a1 * a1, a2 * a2, a3 * a3,
                  a4 * a4, a5 * a5, a6 * a6, a7 * a7};
    #pragma unroll
    for (int k = 0; k < 8; ++k) {
        s[k] += __shfl_xor(s[k], 16, 64);
        s[k] += __shfl_xor(s[k], 32, 64);
        q[k] += __shfl_xor(q[k], 16, 64);
        q[k] += __shfl_xor(q[k], 32, 64);
    }
    const int w = t >> 6, l = t & 63;
    if (l < 16) {
        float* wr = &wred[w][l * 8];
        #pragma unroll
        for (int k = 0; k < 8; ++k) { wr[k] = s[k]; wr[128 + k] = q[k]; }
    }
    __threadfence_block();                 // drain LDS writes before counting
    int old = 0;
    if (l == 0) old = atomicAdd(&cnt[blockIdx.x], 1);
    old = __shfl(old, 0, 64);
    if (old == 3) {                        // last wave: flush block total
        __threadfence_block();             // acquire: see other waves' regions
        const int base = (blockIdx.x & 7) * 256;
        #pragma unroll
        for (int i = 0; i < 4; ++i) {
            int m = l + 64 * i;
            float v = wred[0][m] + wred[1][m] + wred[2][m] + wred[3][m];
            unsafeAtomicAdd(&stats[base + m], v);
        }
    }
}

// 40-ch final from line-aligned stride-64 H (1 cache line per gathered row)
__global__ __launch_bounds__(256) void k_agg40(
        const unsigned short* __restrict__ H, const int* __restrict__ rs,
        const int* __restrict__ re, const int* __restrict__ csr,
        const float* __restrict__ dinv, const float* __restrict__ b,
        float* __restrict__ out, int N) {
    int lane = threadIdx.x & 15;
    int node = blockIdx.x * 16 + (threadIdx.x >> 4);
    if (node >= N || lane >= 10) return;
    float dd  = dinv[node];
    int   beg = rs[node];
    int   end = re[node];
    uint2 hp  = ((const uint2*)(H + (size_t)node * 64))[lane];
    float4 bb = ((const float4*)b)[lane];
    float  sl = dd * dd;
    float4 acc = make_float4(fmaf(bflo(hp.x), sl, bb.x), fmaf(bfhi(hp.x), sl, bb.y),
                             fmaf(bflo(hp.y), sl, bb.z), fmaf(bfhi(hp.y), sl, bb.w));
    int j = beg;
    for (; j + 2 <= end; j += 2) {
        int s0 = csr[j], s1 = csr[j + 1];
        float n0 = dinv[s0] * dd, n1 = dinv[s1] * dd;
        uint2 v0 = ((const uint2*)(H + (size_t)s0 * 64))[lane];
        uint2 v1 = ((const uint2*)(H + (size_t)s1 * 64))[lane];
        acc.x = fmaf(bflo(v0.x), n0, fmaf(bflo(v1.x), n1, acc.x));
        acc.y = fmaf(bfhi(v0.x), n0, fmaf(bfhi(v1.x), n1, acc.y));
        acc.z = fmaf(bflo(v0.y), n0, fmaf(bflo(v1.y), n1, acc.z));
        acc.w = fmaf(bfhi(v0.y), n0, fmaf(bfhi(v1.y), n1, acc.w));
    }
    if (j < end) {
        int s0 = csr[j];
        float n0 = dinv[s0] * dd;
        uint2 v0 = ((const uint2*)(H + (size_t)s0 * 64))[lane];
        acc.x = fmaf(bflo(v0.x), n0, acc.x);
        acc.y = fmaf(bfhi(v0.x), n0, acc.y);
        acc.z = fmaf(bflo(v0.y), n0, acc.z);
        acc.w = fmaf(bfhi(v0.y), n0, acc.w);
    }
    ((float4*)(out + (size_t)node * 40))[lane] = acc;
}

// ================================ launch ====================================
extern "C" void kernel_launch(void* const* d_in, const int* in_sizes, int n_in,
                              void* d_out, int out_size, void* d_ws, size_t ws_size,
                              hipStream_t stream) {
    const float* x   = (const float*)d_in[0];
    const int*   ei  = (const int*)d_in[1];      // int64 in ref -> int32 from harness
    const float* W0  = (const float*)d_in[2];
    const float* b0  = (const float*)d_in[3];
    const float* g0  = (const float*)d_in[4];
    const float* be0 = (const float*)d_in[5];
    const float* W1  = (const float*)d_in[6];
    const float* b1  = (const float*)d_in[7];
    const float* g1  = (const float*)d_in[8];
    const float* be1 = (const float*)d_in[9];
    const float* W2  = (const float*)d_in[10];
    const float* b2  = (const float*)d_in[11];
    float* out = (float*)d_out;

    const int N  = in_sizes[0] / 128;   // 170000
    const int E  = in_sizes[1] / 2;     // 1200000
    const int NB = (N + 255) >> 8;      // 665 buckets
    const int EB = (E + 8191) / 8192;   // 147 edge-chunk blocks

    // ws layout (4B units)
    float* ws   = (float*)d_ws;
    size_t Npad = ((size_t)N + 511) & ~(size_t)511;
    size_t BCAP = (size_t)NB * CAP;
    float* dinv = ws;
    int*   rs   = (int*)(ws + Npad);
    int*   re   = rs + Npad;
    int*   csr  = re + Npad;                            // BCAP
    unsigned int* ebuf = (unsigned int*)(csr + BCAP);   // BCAP
    int*   bcur = (int*)(ebuf + BCAP);                  // 1024
    float* stats0 = (float*)(bcur + 1024);              // 8 slabs x 256
    float* stats1 = stats0 + 2048;                      // 8 slabs x 256
    int*   cnt0  = (int*)(stats1 + 2048);               // CNT_STRIDE
    int*   cnt1  = cnt0 + CNT_STRIDE;                   // CNT_STRIDE
    unsigned short* Wf = (unsigned short*)(cnt1 + CNT_STRIDE); // 3*16384 ushort
    unsigned short* Hb = Wf + 3 * 16384;                // Npad*128 bf16
    unsigned short* Bb = Hb + Npad * 128;               // Npad*128 bf16

    int gemm_grid = (N + 63) / 64;
    int agg_grid  = (N + 15) / 16;

    // ---- dispatch 1: Wf prep + bcur/stats/cnt init (must precede bscatter) --
    k_prepW3  <<<24, 256, 0, stream>>>(W0, W1, W2, Wf, bcur, stats0, cnt0, NB);
    // ---- dispatch 2: edge scatter ----
    k_bscatter<<<EB, 256, 0, stream>>>(ei, bcur, ebuf, E, NB);
    // ---- dispatch 3: CSR finalize || layer-0 GEMM (independent roles) ----
    k_final_gemm0<<<NB + gemm_grid, 256, 0, stream>>>(ebuf, bcur, csr, rs, re,
                                                      dinv, x, Wf, Hb, N, NB);

    // ---- layer 0 aggregate (+ fused BN0 stats, last-wave-flush tail) ----
    k_agg128<<<agg_grid, 256, 0, stream>>>(Hb, rs, re, csr, dinv, b0, Bb,
                                           stats0, cnt0, N);

    // ---- layer 1 (BN0+ReLU fused into GEMM staging); agg fuses BN1 stats ----
    k_gemm_mfma<8, 128><<<gemm_grid, 256, 0, stream>>>(Bb, Wf + 16384, Hb, N,
                                                       stats0, g0, be0);
    k_agg128<<<agg_grid, 256, 0, stream>>>(Hb, rs, re, csr, dinv, b1, Bb,
                                           stats1, cnt1, N);

    // ---- layer 2 (BN1+ReLU fused) -> line-aligned 64-stride H -> 40-ch out ----
    k_gemm_mfma<3, 64><<<gemm_grid, 256, 0, stream>>>(Bb, Wf + 2 * 16384, Hb, N,
                                                      stats1, g1, be1);
    k_agg40<<<agg_grid, 256, 0, stream>>>(Hb, rs, re, csr, dinv, b2, out, N);
}

// Round 14
// 433.913 us; speedup vs baseline: 5.4413x; 1.0050x over previous
//
#include <hip/hip_runtime.h>

#define BN_EPS 1e-5f
#define CAP 3072   // per-bucket edge capacity (mean 1805, +30 sigma; guarded)
#define CNT_STRIDE 16384   // per-launch block-counter array (>= agg_grid)

using bf16x8 = __attribute__((ext_vector_type(8))) short;
using f32x4  = __attribute__((ext_vector_type(4))) float;

__device__ __forceinline__ unsigned int f2bf(float f) {   // RTNE fp32->bf16
    unsigned int u = __float_as_uint(f);
    u += 0x7fffu + ((u >> 16) & 1u);
    return u >> 16;
}
// packed RTNE fp32x2 -> bf16x2 (bit-identical to f2bf pair)
__device__ __forceinline__ unsigned int f2bf2(float lo, float hi) {
    unsigned int r;
    asm("v_cvt_pk_bf16_f32 %0, %1, %2" : "=v"(r) : "v"(lo), "v"(hi));
    return r;
}
__device__ __forceinline__ float bflo(unsigned int u) { return __uint_as_float(u << 16); }
__device__ __forceinline__ float bfhi(unsigned int u) { return __uint_as_float(u & 0xffff0000u); }

// ========= dispatch 1: weight prep (+ bcur/stats/cnt init, own dispatch) ====
// MUST complete before k_bscatter (bcur init -> atomicAdd ordering).
__global__ __launch_bounds__(256) void k_prepW3(const float* __restrict__ W0,
                                                const float* __restrict__ W1,
                                                const float* __restrict__ W2,
                                                unsigned short* __restrict__ Wf,
                                                int* __restrict__ bcur,
                                                float* __restrict__ stats,
                                                int* __restrict__ cnt, int NB) {
    int t = blockIdx.x * 256 + threadIdx.x;   // 0..6143
    if (t < NB) bcur[t] = t * CAP;            // folded k_init
    if (t < 4096) stats[t] = 0.f;             // zeroes stats0+stats1 slabs
    for (int z = t; z < 2 * CNT_STRIDE; z += 6144) cnt[z] = 0;  // flush counters
    int wid = t >> 11;                        // 0,1,2
    int f = t & 2047;
    const float* W = (wid == 0) ? W0 : (wid == 1) ? W1 : W2;
    int C = (wid == 2) ? 40 : 128;
    int lane = f & 63, frag = f >> 6;
    int kt = frag & 3, ct = frag >> 2;
    int r = lane & 15, q = lane >> 4;
    int col = ct * 16 + r;
    int kbase = kt * 32 + q * 8;
    unsigned int v[8];
    #pragma unroll
    for (int j = 0; j < 8; ++j)
        v[j] = (col < C) ? f2bf(W[(size_t)(kbase + j) * C + col]) : 0u;
    uint4 o;
    o.x = v[0] | (v[1] << 16);
    o.y = v[2] | (v[3] << 16);
    o.z = v[4] | (v[5] << 16);
    o.w = v[6] | (v[7] << 16);
    ((uint4*)Wf)[t] = o;
}

// ===================== scatter edges into fixed buckets =====================
__global__ __launch_bounds__(256) void k_bscatter(const int* __restrict__ ei,
                                                  int* __restrict__ bcur,
                                                  unsigned int* __restrict__ ebuf,
                                                  int E, int NB) {
    __shared__ int h[768];
    __shared__ int wb[768];
    for (int i = threadIdx.x; i < 768; i += 256) h[i] = 0;
    __syncthreads();
    int base = blockIdx.x * 8192;
    int rk[32];
    #pragma unroll
    for (int it = 0; it < 32; ++it) {
        int e = base + it * 256 + threadIdx.x;
        rk[it] = (e < E) ? atomicAdd(&h[ei[E + e] >> 8], 1) : 0;
    }
    __syncthreads();
    for (int i = threadIdx.x; i < NB; i += 256) {
        int c = h[i];
        wb[i] = c ? atomicAdd(&bcur[i], c) : 0;
    }
    __syncthreads();
    #pragma unroll
    for (int it = 0; it < 32; ++it) {
        int e = base + it * 256 + threadIdx.x;
        if (e < E) {
            unsigned s = (unsigned)ei[e], d = (unsigned)ei[E + e];
            int bk = (int)(d >> 8);
            int pos = wb[bk] + rk[it];
            if (pos >= bk * CAP && pos < (bk + 1) * CAP)   // two-sided guard
                ebuf[pos] = s | ((d & 255u) << 24);
        }
    }
}

// ============ dispatch 3: CSR finalize || layer-0 GEMM (independent) ========
// blocks [0,NB): bfinal role (consumes ebuf/bcur from dispatch 2).
// blocks [NB, NB+gemm_grid): gemm0 role (consumes Wf from dispatch 1 + x).
// No intra-dispatch producer-consumer: race-free.
__global__ __launch_bounds__(256) void k_final_gemm0(
        const unsigned int* __restrict__ ebuf, const int* __restrict__ bcur,
        int* __restrict__ csr, int* __restrict__ rs, int* __restrict__ re,
        float* __restrict__ dinv,
        const float* __restrict__ X, const unsigned short* __restrict__ Wf,
        unsigned short* __restrict__ H, int N, int NB) {
    __shared__ int cnt[256];
    __shared__ int scn[256];
    __shared__ int cur[256];
    __shared__ unsigned short bF[8 * 4 * 512];
    const int t = threadIdx.x;
    if (blockIdx.x < (unsigned)NB) {
        // ---- bfinal role ----
        const int b = blockIdx.x;
        const int beg = b * CAP;
        const int cntE = min(bcur[b] - beg, CAP);
        cnt[t] = 0;
        __syncthreads();
        for (int j = t; j < cntE; j += 256)
            atomicAdd(&cnt[ebuf[beg + j] >> 24], 1);
        __syncthreads();
        int v = cnt[t];
        scn[t] = v;
        __syncthreads();
        for (int off = 1; off < 256; off <<= 1) {
            int x = (t >= off) ? scn[t - off] : 0;
            __syncthreads();
            scn[t] += x;
            __syncthreads();
        }
        int excl = scn[t] - v;
        int node = b * 256 + t;
        if (node < N) {
            rs[node]   = beg + excl;
            re[node]   = beg + excl + v;
            dinv[node] = rsqrtf((float)(1 + v));   // +1 self-loop
        }
        cur[t] = beg + excl;
        __syncthreads();
        for (int j = t; j < cntE; j += 256) {
            unsigned e = ebuf[beg + j];
            int pos = atomicAdd(&cur[e >> 24], 1);
            csr[pos] = (int)(e & 0x00FFFFFFu);
        }
        return;
    }
    // ---- gemm0 role: H[N,128] = bf16(X[N,128]_f32 @ W0) ----
    const int rowbase = (blockIdx.x - NB) * 64;
    {   // stage B: 8 col-tiles
        const uint4* src = (const uint4*)Wf;
        uint4* dst = (uint4*)bF;
        #pragma unroll
        for (int i = 0; i < 8; ++i) dst[t + 256 * i] = src[t + 256 * i];
    }
    __syncthreads();

    const int wave = t >> 6, lane = t & 63;
    const int r = lane & 15, q = lane >> 4;
    const int row  = rowbase + wave * 16 + r;
    const int rowc = min(row, N - 1);          // clamp: OOB rows computed, not stored

    bf16x8 afr[4];
    #pragma unroll
    for (int kt = 0; kt < 4; ++kt) {
        const int kc = kt * 32 + q * 8;
        const float4* xp = (const float4*)(X + (size_t)rowc * 128 + kc);
        float4 p0 = xp[0], p1 = xp[1];
        union { unsigned int u[4]; bf16x8 v; } pk;
        pk.u[0] = f2bf2(p0.x, p0.y);
        pk.u[1] = f2bf2(p0.z, p0.w);
        pk.u[2] = f2bf2(p1.x, p1.y);
        pk.u[3] = f2bf2(p1.z, p1.w);
        afr[kt] = pk.v;
    }

    f32x4 acc[8];
    #pragma unroll
    for (int ct = 0; ct < 8; ++ct) acc[ct] = (f32x4){0.f, 0.f, 0.f, 0.f};
    #pragma unroll
    for (int kt = 0; kt < 4; ++kt) {
        #pragma unroll
        for (int ct = 0; ct < 8; ++ct) {
            bf16x8 b = ((const bf16x8*)bF)[(ct * 4 + kt) * 64 + lane];
            acc[ct] = __builtin_amdgcn_mfma_f32_16x16x32_bf16(afr[kt], b, acc[ct], 0, 0, 0);
        }
    }
    #pragma unroll
    for (int ct = 0; ct < 8; ++ct) {
        #pragma unroll
        for (int i = 0; i < 4; i += 2) {
            int row0 = rowbase + wave * 16 + q * 4 + i;
            unsigned int pk = f2bf2(acc[ct][i], acc[ct][i + 1]);
            if (row0 < N)
                H[(size_t)row0 * 128 + ct * 16 + r] = (unsigned short)pk;
            if (row0 + 1 < N)
                H[(size_t)(row0 + 1) * 128 + ct * 16 + r] = (unsigned short)(pk >> 16);
        }
    }
}

// ============================== MFMA GEMM (layers 1,2) ======================
// No A-LDS: each wave loads its own 16x128 A-tile directly from global in
// MFMA fragment order. BN scale/shift precomputed once per block into LDS
// (stats summed over the 8 contention slabs written by fused agg128).
template <int NOCT, int OST>
__global__ __launch_bounds__(256) void k_gemm_mfma(
        const unsigned short* __restrict__ X, const unsigned short* __restrict__ Wf,
        unsigned short* __restrict__ H, int N,
        const float* __restrict__ stats, const float* __restrict__ g,
        const float* __restrict__ be) {
    __shared__ unsigned short bF[NOCT * 4 * 512];
    __shared__ float2 bnss[128];
    const int tid = threadIdx.x;
    const int rowbase = blockIdx.x * 64;

    if (tid < 128) {
        const float invN = 1.0f / (float)N;
        float se = 0.f, sq = 0.f;
        #pragma unroll
        for (int s = 0; s < 8; ++s) {
            se += stats[s * 256 + tid];
            sq += stats[s * 256 + 128 + tid];
        }
        float mean = se * invN;
        float var  = fmaf(-mean, mean, sq * invN);
        float sc   = g[tid] * rsqrtf(var + BN_EPS);
        bnss[tid]  = make_float2(sc, fmaf(-mean, sc, be[tid]));
    }
    {   // stage B: NOCT col-tiles, lane-contiguous copy
        const uint4* src = (const uint4*)Wf;
        uint4* dst = (uint4*)bF;
        #pragma unroll
        for (int i = 0; i < NOCT; ++i) dst[tid + 256 * i] = src[tid + 256 * i];
    }
    __syncthreads();   // bF + bnss ready

    const int wave = tid >> 6, lane = tid & 63;
    const int r = lane & 15, q = lane >> 4;
    const int row  = rowbase + wave * 16 + r;
    const int rowc = min(row, N - 1);          // clamp: OOB rows computed, not stored

    bf16x8 afr[4];
    #pragma unroll
    for (int kt = 0; kt < 4; ++kt) {
        const int kc = kt * 32 + q * 8;
        uint4 p = *((const uint4*)(X + (size_t)rowc * 128 + kc));
        float vv[8];
        vv[0] = bflo(p.x); vv[1] = bfhi(p.x);
        vv[2] = bflo(p.y); vv[3] = bfhi(p.y);
        vv[4] = bflo(p.z); vv[5] = bfhi(p.z);
        vv[6] = bflo(p.w); vv[7] = bfhi(p.w);
        #pragma unroll
        for (int j = 0; j < 8; ++j) {
            float2 ss = bnss[kc + j];
            vv[j] = fmaxf(fmaf(vv[j], ss.x, ss.y), 0.0f);
        }
        union { unsigned int u[4]; bf16x8 v; } pk;
        pk.u[0] = f2bf2(vv[0], vv[1]);
        pk.u[1] = f2bf2(vv[2], vv[3]);
        pk.u[2] = f2bf2(vv[4], vv[5]);
        pk.u[3] = f2bf2(vv[6], vv[7]);
        afr[kt] = pk.v;
    }

    f32x4 acc[NOCT];
    #pragma unroll
    for (int ct = 0; ct < NOCT; ++ct) acc[ct] = (f32x4){0.f, 0.f, 0.f, 0.f};

    #pragma unroll
    for (int kt = 0; kt < 4; ++kt) {
        #pragma unroll
        for (int ct = 0; ct < NOCT; ++ct) {
            bf16x8 b = ((const bf16x8*)bF)[(ct * 4 + kt) * 64 + lane];
            acc[ct] = __builtin_amdgcn_mfma_f32_16x16x32_bf16(afr[kt], b, acc[ct], 0, 0, 0);
        }
    }

    // C/D: col = ct*16 + r, row = q*4 + i; pack row-pairs, split halves
    #pragma unroll
    for (int ct = 0; ct < NOCT; ++ct) {
        #pragma unroll
        for (int i = 0; i < 4; i += 2) {
            int row0 = rowbase + wave * 16 + q * 4 + i;
            unsigned int pk = f2bf2(acc[ct][i], acc[ct][i + 1]);
            if (row0 < N)
                H[(size_t)row0 * OST + ct * 16 + r] = (unsigned short)pk;
            if (row0 + 1 < N)
                H[(size_t)(row0 + 1) * OST + ct * 16 + r] = (unsigned short)(pk >> 16);
        }
    }
}

// ================ gather-based aggregate + fused BN stats ===================
// 16 lanes/node, uint4 (8ch) per lane — round-0 gather structure. Stats tail
// is BARRIER-FREE last-wave-flush. Release fence narrowed to lgkmcnt(0):
// only LDS ordering is needed (ds_write executed before the cnt bump; LDS is
// block-local and uncached). No vmcnt drain -> waves exit without waiting
// on their VMEM queue.
__global__ __launch_bounds__(256) void k_agg128(
        const unsigned short* __restrict__ H, const int* __restrict__ rs,
        const int* __restrict__ re, const int* __restrict__ csr,
        const float* __restrict__ dinv, const float* __restrict__ b,
        unsigned short* __restrict__ outb, float* __restrict__ stats,
        int* __restrict__ cnt, int N) {
    __shared__ float wred[4][256];   // per-wave 1KB partial region
    const int t = threadIdx.x;
    int lane = t & 15;
    int node = blockIdx.x * 16 + (t >> 4);
    const bool valid = node < N;
    const int nodec = valid ? node : 0;
    float dd  = dinv[nodec];
    int   beg = rs[nodec];
    int   end = valid ? re[nodec] : beg;   // invalid -> empty edge loop
    uint4 hp  = ((const uint4*)(H + (size_t)nodec * 128))[lane];
    float4 bb0 = ((const float4*)b)[lane * 2];
    float4 bb1 = ((const float4*)b)[lane * 2 + 1];
    float sl = dd * dd;
    float a0 = fmaf(bflo(hp.x), sl, bb0.x), a1 = fmaf(bfhi(hp.x), sl, bb0.y);
    float a2 = fmaf(bflo(hp.y), sl, bb0.z), a3 = fmaf(bfhi(hp.y), sl, bb0.w);
    float a4 = fmaf(bflo(hp.z), sl, bb1.x), a5 = fmaf(bfhi(hp.z), sl, bb1.y);
    float a6 = fmaf(bflo(hp.w), sl, bb1.z), a7 = fmaf(bfhi(hp.w), sl, bb1.w);
    int j = beg;
    for (; j + 2 <= end; j += 2) {
        int s0 = csr[j], s1 = csr[j + 1];
        float n0 = dinv[s0] * dd, n1 = dinv[s1] * dd;
        uint4 v0 = ((const uint4*)(H + (size_t)s0 * 128))[lane];
        uint4 v1 = ((const uint4*)(H + (size_t)s1 * 128))[lane];
        a0 = fmaf(bflo(v0.x), n0, fmaf(bflo(v1.x), n1, a0));
        a1 = fmaf(bfhi(v0.x), n0, fmaf(bfhi(v1.x), n1, a1));
        a2 = fmaf(bflo(v0.y), n0, fmaf(bflo(v1.y), n1, a2));
        a3 = fmaf(bfhi(v0.y), n0, fmaf(bfhi(v1.y), n1, a3));
        a4 = fmaf(bflo(v0.z), n0, fmaf(bflo(v1.z), n1, a4));
        a5 = fmaf(bfhi(v0.z), n0, fmaf(bfhi(v1.z), n1, a5));
        a6 = fmaf(bflo(v0.w), n0, fmaf(bflo(v1.w), n1, a6));
        a7 = fmaf(bfhi(v0.w), n0, fmaf(bfhi(v1.w), n1, a7));
    }
    if (j < end) {
        int s0 = csr[j];
        float n0 = dinv[s0] * dd;
        uint4 v0 = ((const uint4*)(H + (size_t)s0 * 128))[lane];
        a0 = fmaf(bflo(v0.x), n0, a0); a1 = fmaf(bfhi(v0.x), n0, a1);
        a2 = fmaf(bflo(v0.y), n0, a2); a3 = fmaf(bfhi(v0.y), n0, a3);
        a4 = fmaf(bflo(v0.z), n0, a4); a5 = fmaf(bfhi(v0.z), n0, a5);
        a6 = fmaf(bflo(v0.w), n0, a6); a7 = fmaf(bfhi(v0.w), n0, a7);
    }
    if (valid) {
        uint4 o;
        o.x = f2bf2(a0, a1);
        o.y = f2bf2(a2, a3);
        o.z = f2bf2(a4, a5);
        o.w = f2bf2(a6, a7);
        ((uint4*)(outb + (size_t)node * 128))[lane] = o;
    } else {
        a0 = a1 = a2 = a3 = a4 = a5 = a6 = a7 = 0.f;
    }
    // ---- fused BN stats: wave shfl-reduce -> LDS region -> last-wave flush ----
    float s[8] = {a0, a1, a2, a3, a4, a5, a6, a7};
    float q[8] = {a0 * a0, a1 * a1, a2 * a2, a3 * a3,
                  a4 * a4, a5 * a5, a6 * a6, a7 * a7};
    #pragma unroll
    for (int k = 0; k < 8; ++k) {
        s[k] += __shfl_xor(s[k], 16, 64);
        s[k] += __shfl_xor(s[k], 32, 64);
        q[k] += __shfl_xor(q[k], 16, 64);
        q[k] += __shfl_xor(q[k], 32, 64);
    }
    const int w = t >> 6, l = t & 63;
    if (l < 16) {
        float* wr = &wred[w][l * 8];
        #pragma unroll
        for (int k = 0; k < 8; ++k) { wr[k] = s[k]; wr[128 + k] = q[k]; }
    }
    // release: LDS-only ordering (ds_writes executed before cnt bump);
    // no vmcnt drain -> waves exit without waiting on their VMEM queue.
    asm volatile("s_waitcnt lgkmcnt(0)" ::: "memory");
    int old = 0;
    if (l == 0) old = atomicAdd(&cnt[blockIdx.x], 1);
    old = __shfl(old, 0, 64);
    if (old == 3) {                        // last wave: flush block total
        asm volatile("" ::: "memory");     // acquire: compiler barrier;
                                           // HW order via dep on 'old'
        const int base = (blockIdx.x & 7) * 256;
        #pragma unroll
        for (int i = 0; i < 4; ++i) {
            int m = l + 64 * i;
            float v = wred[0][m] + wred[1][m] + wred[2][m] + wred[3][m];
            unsafeAtomicAdd(&stats[base + m], v);
        }
    }
}

// 40-ch final from line-aligned stride-64 H (1 cache line per gathered row)
__global__ __launch_bounds__(256) void k_agg40(
        const unsigned short* __restrict__ H, const int* __restrict__ rs,
        const int* __restrict__ re, const int* __restrict__ csr,
        const float* __restrict__ dinv, const float* __restrict__ b,
        float* __restrict__ out, int N) {
    int lane = threadIdx.x & 15;
    int node = blockIdx.x * 16 + (threadIdx.x >> 4);
    if (node >= N || lane >= 10) return;
    float dd  = dinv[node];
    int   beg = rs[node];
    int   end = re[node];
    uint2 hp  = ((const uint2*)(H + (size_t)node * 64))[lane];
    float4 bb = ((const float4*)b)[lane];
    float  sl = dd * dd;
    float4 acc = make_float4(fmaf(bflo(hp.x), sl, bb.x), fmaf(bfhi(hp.x), sl, bb.y),
                             fmaf(bflo(hp.y), sl, bb.z), fmaf(bfhi(hp.y), sl, bb.w));
    int j = beg;
    for (; j + 2 <= end; j += 2) {
        int s0 = csr[j], s1 = csr[j + 1];
        float n0 = dinv[s0] * dd, n1 = dinv[s1] * dd;
        uint2 v0 = ((const uint2*)(H + (size_t)s0 * 64))[lane];
        uint2 v1 = ((const uint2*)(H + (size_t)s1 * 64))[lane];
        acc.x = fmaf(bflo(v0.x), n0, fmaf(bflo(v1.x), n1, acc.x));
        acc.y = fmaf(bfhi(v0.x), n0, fmaf(bfhi(v1.x), n1, acc.y));
        acc.z = fmaf(bflo(v0.y), n0, fmaf(bflo(v1.y), n1, acc.z));
        acc.w = fmaf(bfhi(v0.y), n0, fmaf(bfhi(v1.y), n1, acc.w));
    }
    if (j < end) {
        int s0 = csr[j];
        float n0 = dinv[s0] * dd;
        uint2 v0 = ((const uint2*)(H + (size_t)s0 * 64))[lane];
        acc.x = fmaf(bflo(v0.x), n0, acc.x);
        acc.y = fmaf(bfhi(v0.x), n0, acc.y);
        acc.z = fmaf(bflo(v0.y), n0, acc.z);
        acc.w = fmaf(bfhi(v0.y), n0, acc.w);
    }
    ((float4*)(out + (size_t)node * 40))[lane] = acc;
}

// ================================ launch ====================================
extern "C" void kernel_launch(void* const* d_in, const int* in_sizes, int n_in,
                              void* d_out, int out_size, void* d_ws, size_t ws_size,
                              hipStream_t stream) {
    const float* x   = (const float*)d_in[0];
    const int*   ei  = (const int*)d_in[1];      // int64 in ref -> int32 from harness
    const float* W0  = (const float*)d_in[2];
    const float* b0  = (const float*)d_in[3];
    const float* g0  = (const float*)d_in[4];
    const float* be0 = (const float*)d_in[5];
    const float* W1  = (const float*)d_in[6];
    const float* b1  = (const float*)d_in[7];
    const float* g1  = (const float*)d_in[8];
    const float* be1 = (const float*)d_in[9];
    const float* W2  = (const float*)d_in[10];
    const float* b2  = (const float*)d_in[11];
    float* out = (float*)d_out;

    const int N  = in_sizes[0] / 128;   // 170000
    const int E  = in_sizes[1] / 2;     // 1200000
    const int NB = (N + 255) >> 8;      // 665 buckets
    const int EB = (E + 8191) / 8192;   // 147 edge-chunk blocks

    // ws layout (4B units)
    float* ws   = (float*)d_ws;
    size_t Npad = ((size_t)N + 511) & ~(size_t)511;
    size_t BCAP = (size_t)NB * CAP;
    float* dinv = ws;
    int*   rs   = (int*)(ws + Npad);
    int*   re   = rs + Npad;
    int*   csr  = re + Npad;                            // BCAP
    unsigned int* ebuf = (unsigned int*)(csr + BCAP);   // BCAP
    int*   bcur = (int*)(ebuf + BCAP);                  // 1024
    float* stats0 = (float*)(bcur + 1024);              // 8 slabs x 256
    float* stats1 = stats0 + 2048;                      // 8 slabs x 256
    int*   cnt0  = (int*)(stats1 + 2048);               // CNT_STRIDE
    int*   cnt1  = cnt0 + CNT_STRIDE;                   // CNT_STRIDE
    unsigned short* Wf = (unsigned short*)(cnt1 + CNT_STRIDE); // 3*16384 ushort
    unsigned short* Hb = Wf + 3 * 16384;                // Npad*128 bf16
    unsigned short* Bb = Hb + Npad * 128;               // Npad*128 bf16

    int gemm_grid = (N + 63) / 64;
    int agg_grid  = (N + 15) / 16;

    // ---- dispatch 1: Wf prep + bcur/stats/cnt init (must precede bscatter) --
    k_prepW3  <<<24, 256, 0, stream>>>(W0, W1, W2, Wf, bcur, stats0, cnt0, NB);
    // ---- dispatch 2: edge scatter ----
    k_bscatter<<<EB, 256, 0, stream>>>(ei, bcur, ebuf, E, NB);
    // ---- dispatch 3: CSR finalize || layer-0 GEMM (independent roles) ----
    k_final_gemm0<<<NB + gemm_grid, 256, 0, stream>>>(ebuf, bcur, csr, rs, re,
                                                      dinv, x, Wf, Hb, N, NB);

    // ---- layer 0 aggregate (+ fused BN0 stats, last-wave-flush tail) ----
    k_agg128<<<agg_grid, 256, 0, stream>>>(Hb, rs, re, csr, dinv, b0, Bb,
                                           stats0, cnt0, N);

    // ---- layer 1 (BN0+ReLU fused into GEMM staging); agg fuses BN1 stats ----
    k_gemm_mfma<8, 128><<<gemm_grid, 256, 0, stream>>>(Bb, Wf + 16384, Hb, N,
                                                       stats0, g0, be0);
    k_agg128<<<agg_grid, 256, 0, stream>>>(Hb, rs, re, csr, dinv, b1, Bb,
                                           stats1, cnt1, N);

    // ---- layer 2 (BN1+ReLU fused) -> line-aligned 64-stride H -> 40-ch out ----
    k_gemm_mfma<3, 64><<<gemm_grid, 256, 0, stream>>>(Bb, Wf + 2 * 16384, Hb, N,
                                                      stats1, g1, be1);
    k_agg40<<<agg_grid, 256, 0, stream>>>(Hb, rs, re, csr, dinv, b2, out, N);
}